// Round 1
// baseline (29505.930 us; speedup 1.0000x reference)
//
#include <hip/hip_runtime.h>
#include <math.h>

#define BB 64
#define TT 256
#define HH 512
#define G4 2048              // 4*H
#define TH (TT*HH)           // 131072
#define BTH (BB*TT*HH)       // 8388608 per-layer out stride

struct SegDesc {
    const float* src;   // pre-offset by t*H (or (t-1)*H); index with b*TH + kin
    const float* w;     // pre-offset by column start; index with j*wstride + kin
    int wstride;
    int scalesel;       // 0 = d_bottom, 1 = d, 2 = 1.0
    int zero;           // force zeros (t==0 guards)
};

struct GemmArgs {
    SegDesc seg[4];
    int nseg;
    const float* dx;
    int l, t;
    float* gp;          // [8][64][2048] split-K partials
};

// 64 j-cols x 64 batches tile, split-K over blockIdx.y (8 splits).
__global__ __launch_bounds__(256) void gates_gemm(GemmArgs a) {
    __shared__ float sW[32][65];
    __shared__ float sX[32][65];
    __shared__ float sDB[64];
    __shared__ float sD[64];
    const int tid = threadIdx.x;
    const int jb  = blockIdx.x;      // 0..31
    const int ks  = blockIdx.y;      // 0..7
    const int Ktot = a.nseg * 512;
    const int kbeg = ks * (Ktot >> 3);
    const int kend = kbeg + (Ktot >> 3);

    if (tid < 64) {
        int b = tid;
        sDB[b] = (a.l == 0) ? 1.0f : a.dx[b*768 + (a.l-1)*256 + a.t];
        sD[b]  = (a.t == 0) ? 0.0f : a.dx[b*768 + a.l*256 + (a.t-1)];
    }

    float acc[4][4] = {};
    const int ty = tid >> 4;    // 0..15 -> batch group
    const int tx = tid & 15;    // 0..15 -> j group
    const int lk = tid & 31;    // k within chunk for loads
    const int lr0 = tid >> 5;   // 0..7 row group for loads

    for (int k0 = kbeg; k0 < kend; k0 += 32) {
        const int seg = k0 >> 9;
        const SegDesc s = a.seg[seg];
        const int kin = k0 & 511;
        __syncthreads();   // protect previous-iter LDS reads (and sDB/sD init)
        #pragma unroll
        for (int r = 0; r < 8; ++r) {
            const int lr = r*8 + lr0;   // 0..63
            sW[lk][lr] = s.w[(size_t)(jb*64 + lr)*s.wstride + kin + lk];
            float xv = 0.0f;
            if (!s.zero) {
                xv = s.src[(size_t)lr*TH + kin + lk];
                float sc = (s.scalesel == 0) ? sDB[lr] : ((s.scalesel == 1) ? sD[lr] : 1.0f);
                xv *= sc;
            }
            sX[lk][lr] = xv;
        }
        __syncthreads();
        #pragma unroll
        for (int kk = 0; kk < 32; ++kk) {
            float xr[4], wr[4];
            #pragma unroll
            for (int i = 0; i < 4; ++i) xr[i] = sX[kk][ty*4 + i];
            #pragma unroll
            for (int j = 0; j < 4; ++j) wr[j] = sW[kk][tx*4 + j];
            #pragma unroll
            for (int i = 0; i < 4; ++i)
                #pragma unroll
                for (int j = 0; j < 4; ++j)
                    acc[i][j] = fmaf(xr[i], wr[j], acc[i][j]);
        }
    }
    #pragma unroll
    for (int i = 0; i < 4; ++i) {
        const int b = ty*4 + i;
        float4 v = make_float4(acc[i][0], acc[i][1], acc[i][2], acc[i][3]);
        *(float4*)&a.gp[((size_t)ks*64 + b)*2048 + jb*64 + tx*4] = v;
    }
}

__global__ __launch_bounds__(256) void cell_kernel(
    const float* __restrict__ gp, const float* __restrict__ b_ih,
    const float* __restrict__ b_hh, const float* __restrict__ dx,
    float* __restrict__ out, float* __restrict__ cst, int l, int t)
{
    const int idx = blockIdx.x * 256 + threadIdx.x;  // 0..32767
    const int b = idx >> 9;
    const int k = idx & 511;
    const float db = (l == 0) ? 1.0f : dx[b*768 + (l-1)*256 + t];
    const float d  = (t == 0) ? 0.0f : dx[b*768 + l*256 + (t-1)];

    float gi = 0.f, gf = 0.f, gg = 0.f, go = 0.f;
    #pragma unroll
    for (int s = 0; s < 8; ++s) {
        const float* base = gp + ((size_t)s*64 + b)*2048;
        gi += base[k];
        gf += base[512 + k];
        gg += base[1024 + k];
        go += base[1536 + k];
    }
    gi += b_ih[k]        + b_hh[k];
    gf += b_ih[512 + k]  + b_hh[512 + k];
    gg += b_ih[1024 + k] + b_hh[1024 + k];
    go += b_ih[1536 + k] + b_hh[1536 + k];

    const float i_ = 1.0f / (1.0f + expf(-gi));
    const float f_ = 1.0f / (1.0f + expf(-gf));
    const float g_ = tanhf(gg);
    const float o_ = 1.0f / (1.0f + expf(-go));

    const float cp = cst[(size_t)l*BB*HH + idx];
    const float c  = cp * (1.0f - d);
    const float c_ = f_*c + i_*g_;
    const float h_ = o_ * tanhf(c_);
    const float hp = (t == 0) ? 0.0f : out[(size_t)l*BTH + (size_t)b*TH + (size_t)(t-1)*HH + k];

    const bool copy = (db + d == 0.0f);
    out[(size_t)l*BTH + (size_t)b*TH + (size_t)t*HH + k] = copy ? hp : h_;
    cst[(size_t)l*BB*HH + idx] = copy ? c : c_;
}

extern "C" void kernel_launch(void* const* d_in, const int* in_sizes, int n_in,
                              void* d_out, int out_size, void* d_ws, size_t ws_size,
                              hipStream_t stream) {
    const float* x[3]    = {(const float*)d_in[0], (const float*)d_in[1], (const float*)d_in[2]};
    const float* dx      = (const float*)d_in[3];
    const float* W_ih[3] = {(const float*)d_in[4], (const float*)d_in[8],  (const float*)d_in[12]};
    const float* W_hh[3] = {(const float*)d_in[5], (const float*)d_in[9],  (const float*)d_in[13]};
    const float* b_ih[3] = {(const float*)d_in[6], (const float*)d_in[10], (const float*)d_in[14]};
    const float* b_hh[3] = {(const float*)d_in[7], (const float*)d_in[11], (const float*)d_in[15]};
    float* out = (float*)d_out;
    float* cst = (float*)d_ws;               // 3*64*512 floats c-state
    float* gp  = cst + 3*BB*HH;              // 8*64*2048 floats split-K partials
    const int CELL_IN[3] = {1024, 1536, 1024};

    hipMemsetAsync(cst, 0, (size_t)3*BB*HH*sizeof(float), stream);

    for (int t = 0; t < TT; ++t) {
        for (int l = 0; l < 3; ++l) {
            GemmArgs a;
            a.dx = dx; a.l = l; a.t = t; a.gp = gp;
            int ns = 0;
            // seg 0: x * d_bottom  (d_bottom == 1 for l==0)
            a.seg[ns++] = {x[l] + (size_t)t*HH, W_ih[l], CELL_IN[l], (l == 0) ? 2 : 0, 0};
            if (l > 0)  // bottom-up: h_new[l-1] at t, scale d_bottom
                a.seg[ns++] = {out + (size_t)(l-1)*BTH + (size_t)t*HH,
                               W_ih[l] + 512, CELL_IN[l], 0, 0};
            if (l < 2)  // top-down: h_prev[l+1] at t-1, scale d
                a.seg[ns++] = {out + (size_t)(l+1)*BTH + (size_t)(t-1)*HH,
                               W_ih[l] + (l == 0 ? 512 : 1024), CELL_IN[l], 1, (t == 0) ? 1 : 0};
            // recurrent: h_prev[l] at t-1, scale 1, W_hh
            a.seg[ns++] = {out + (size_t)l*BTH + (size_t)(t-1)*HH,
                           W_hh[l], 512, 2, (t == 0) ? 1 : 0};
            a.nseg = ns;
            gates_gemm<<<dim3(32, 8), 256, 0, stream>>>(a);
            cell_kernel<<<dim3(128), 256, 0, stream>>>(gp, b_ih[l], b_hh[l], dx, out, cst, l, t);
        }
    }
}

// Round 2
// 8115.022 us; speedup vs baseline: 3.6360x; 3.6360x over previous
//
#include <hip/hip_runtime.h>
#include <math.h>

#define BB 64
#define TT 256
#define HH 512
#define TH (TT*HH)
#define BTH (BB*TT*HH)

typedef __attribute__((ext_vector_type(8))) short short8;
typedef __attribute__((ext_vector_type(4))) float f32x4;

__device__ __forceinline__ unsigned short f32_bf16(float f) {
    unsigned int u = __float_as_uint(f);
    return (unsigned short)((u + 0x7fffu + ((u >> 16) & 1u)) >> 16);
}

// ---- one-time: weights fp32 -> bf16 in MFMA-fragment-major layout ----
// region layout: 10 regions of 2048x512, flat elem e = (nt*16+kc)*512 + lane*8 + j
// maps to W[n = nt*16 + (lane&15)][co + kc*32 + (lane>>4)*8 + j]
struct WConv {
    const float* src[10];
    int rs[10];
    int co[10];
    short* dst;
};
__global__ __launch_bounds__(256) void conv_w(WConv a) {
    const int rid = blockIdx.y;
    const int i = blockIdx.x * 256 + threadIdx.x;      // 0..131071
    const int lane = i & 63;
    const int kc = (i >> 6) & 15;
    const int nt = i >> 10;                             // 0..127
    const int n = nt * 16 + (lane & 15);
    const int kb = kc * 32 + (lane >> 4) * 8;
    const float* s = a.src[rid] + (size_t)n * a.rs[rid] + a.co[rid] + kb;
    float4 v0 = *(const float4*)s;
    float4 v1 = *(const float4*)(s + 4);
    short8 o;
    o[0]=f32_bf16(v0.x); o[1]=f32_bf16(v0.y); o[2]=f32_bf16(v0.z); o[3]=f32_bf16(v0.w);
    o[4]=f32_bf16(v1.x); o[5]=f32_bf16(v1.y); o[6]=f32_bf16(v1.z); o[7]=f32_bf16(v1.w);
    *(short8*)(a.dst + (size_t)rid * 1048576 + (size_t)i * 8) = o;
}

// ---- one-time: x fp32 -> bf16 fragment-major: per layer, elem
// e = ((t*4+bt)*16 + kc)*512 + lane*8 + j  <->  x[b=bt*16+(lane&15)][t][kc*32+(lane>>4)*8+j]
struct XConv {
    const float* src[3];
    short* dst;
};
__global__ __launch_bounds__(256) void conv_x(XConv a) {
    const int l = blockIdx.y;
    const int i = blockIdx.x * 256 + threadIdx.x;      // 0..1048575
    const int lane = i & 63;
    const int kc = (i >> 6) & 15;
    const int btt = i >> 10;                            // 0..1023
    const int bt = btt & 3;
    const int t = btt >> 2;
    const int b = bt * 16 + (lane & 15);
    const int k = kc * 32 + (lane >> 4) * 8;
    const float* s = a.src[l] + ((size_t)b * TT + t) * HH + k;
    float4 v0 = *(const float4*)s;
    float4 v1 = *(const float4*)(s + 4);
    short8 o;
    o[0]=f32_bf16(v0.x); o[1]=f32_bf16(v0.y); o[2]=f32_bf16(v0.z); o[3]=f32_bf16(v0.w);
    o[4]=f32_bf16(v1.x); o[5]=f32_bf16(v1.y); o[6]=f32_bf16(v1.z); o[7]=f32_bf16(v1.w);
    *(short8*)(a.dst + (size_t)l * 8388608 + (size_t)i * 8) = o;
}

// ---- per-stage fused gates-GEMM + LSTM cell ----
// grid (32 c-blocks, 4 b-blocks), 512 thr = 8 waves = 4 gates x 2 K-halves.
// Wave (q,half) accumulates D[16b x 16c] for gate q over its K half. All
// operand loads are coalesced dwordx4 from fragment-major bf16 buffers.
struct Stage {
    const short* ap[4];   // A fragment region base (kernel adds bt*8192 + kc*512 + lane*8)
    const short* wp[4];   // W fragment region base
    int sel[4];           // 0: scale d_bottom, 1: scale d, 2: scale 1
    int nseg, l, t;
    const float* dx; const float* bih; const float* bhh;
    float* out; float* cst; short* hdst;
};
__global__ __launch_bounds__(512) void stage_kernel(Stage a) {
    __shared__ float g[8][16][17];
    const int tid = threadIdx.x;
    const int lane = tid & 63;
    const int wave = tid >> 6;
    const int q = wave & 3;
    const int half = wave >> 2;
    const int cb = blockIdx.x;          // 0..31
    const int bt = blockIdx.y;          // 0..3
    const int r16 = lane & 15;
    const int b_lane = bt * 16 + r16;

    const float dbv = (a.l == 0) ? 1.f : a.dx[b_lane * 768 + (a.l - 1) * 256 + a.t];
    const float dv  = (a.t == 0) ? 0.f : a.dx[b_lane * 768 + a.l * 256 + a.t - 1];

    const int Khalf = a.nseg * 256;
    const int kbeg = half * Khalf;
    const int kend = kbeg + Khalf;

    f32x4 acc = {0.f, 0.f, 0.f, 0.f};
    const short8 vzero = {0, 0, 0, 0, 0, 0, 0, 0};
    const int aoff = bt * 8192 + lane * 8;
    const int woff = (q * 32 + cb) * 16 * 512 + lane * 8;

    #pragma unroll
    for (int s = 0; s < 4; ++s) {
        if (s < a.nseg) {
            int lo = kbeg - s * 512; lo = lo < 0 ? 0 : lo;
            int hi = kend - s * 512; hi = hi > 512 ? 512 : hi;
            if (lo < hi) {
                const int sel = a.sel[s];
                const float sc = (sel == 0) ? dbv : ((sel == 1) ? dv : 1.f);
                const bool nz = (sc != 0.f);
                const short* ap = a.ap[s] + aoff + (lo >> 5) * 512;
                const short* wp = a.wp[s] + woff + (lo >> 5) * 512;
                for (int kin = lo; kin < hi; kin += 32) {
                    short8 av = *(const short8*)ap;
                    short8 bv = *(const short8*)wp;
                    ap += 512; wp += 512;
                    av = nz ? av : vzero;   // d / d_bottom are exactly 0 or 1
                    acc = __builtin_amdgcn_mfma_f32_16x16x32_bf16(av, bv, acc, 0, 0, 0);
                }
            }
        }
    }

    // D layout: lane holds D[m = (lane>>4)*4 + r][n = lane&15]
    #pragma unroll
    for (int r = 0; r < 4; ++r)
        g[wave][(lane >> 4) * 4 + r][r16] = acc[r];
    __syncthreads();

    if (tid < 256) {
        const int b_i = tid >> 4, c_i = tid & 15;
        const int b = bt * 16 + b_i;
        const int c = cb * 16 + c_i;
        float gi = g[0][b_i][c_i] + g[4][b_i][c_i] + a.bih[c]        + a.bhh[c];
        float gf = g[1][b_i][c_i] + g[5][b_i][c_i] + a.bih[512 + c]  + a.bhh[512 + c];
        float gg = g[2][b_i][c_i] + g[6][b_i][c_i] + a.bih[1024 + c] + a.bhh[1024 + c];
        float go = g[3][b_i][c_i] + g[7][b_i][c_i] + a.bih[1536 + c] + a.bhh[1536 + c];
        const float db2 = (a.l == 0) ? 1.f : a.dx[b * 768 + (a.l - 1) * 256 + a.t];
        const float d2  = (a.t == 0) ? 0.f : a.dx[b * 768 + a.l * 256 + a.t - 1];
        const float i_ = 1.f / (1.f + expf(-gi));
        const float f_ = 1.f / (1.f + expf(-gf));
        const float g_ = tanhf(gg);
        const float o_ = 1.f / (1.f + expf(-go));
        const size_t ci = ((size_t)a.l * 64 + b) * 512 + c;
        const float cp = a.cst[ci];
        const float cc = cp * (1.f - d2);
        const float cn_ = f_ * cc + i_ * g_;
        const float hn_ = o_ * tanhf(cn_);
        const bool copy = (db2 + d2 == 0.f);
        const float hp = (a.t == 0) ? 0.f
            : a.out[(size_t)a.l * BTH + (size_t)b * TH + (size_t)(a.t - 1) * HH + c];
        const float h  = copy ? hp : hn_;
        const float cn = copy ? cp : cn_;
        a.out[(size_t)a.l * BTH + (size_t)b * TH + (size_t)a.t * HH + c] = h;
        a.cst[ci] = cn;
        // h -> bf16 ring slot in fragment-major order
        const int lane2 = b_i + 16 * ((c & 31) >> 3);
        a.hdst[(bt * 16 + (c >> 5)) * 512 + lane2 * 8 + (c & 7)] = (short)f32_bf16(h);
    }
}

extern "C" void kernel_launch(void* const* d_in, const int* in_sizes, int n_in,
                              void* d_out, int out_size, void* d_ws, size_t ws_size,
                              hipStream_t stream) {
    const float* x[3]    = {(const float*)d_in[0], (const float*)d_in[1], (const float*)d_in[2]};
    const float* dx      = (const float*)d_in[3];
    const float* W_ih[3] = {(const float*)d_in[4], (const float*)d_in[8],  (const float*)d_in[12]};
    const float* W_hh[3] = {(const float*)d_in[5], (const float*)d_in[9],  (const float*)d_in[13]};
    const float* b_ih[3] = {(const float*)d_in[6], (const float*)d_in[10], (const float*)d_in[14]};
    const float* b_hh[3] = {(const float*)d_in[7], (const float*)d_in[11], (const float*)d_in[15]};
    float* out = (float*)d_out;

    // ws layout: cst f32 [3*64*512] | wreg bf16 [10*2048*512] | xreg bf16 [3*64*256*512] | hreg bf16 [3*2*64*512]
    float* cst  = (float*)d_ws;
    short* wreg = (short*)(cst + 3 * BB * HH);
    short* xreg = wreg + (size_t)10 * 1048576;
    short* hreg = xreg + (size_t)3 * 8388608;

    hipMemsetAsync(cst, 0, (size_t)3 * BB * HH * sizeof(float), stream);
    // zero h ring slot 0 for each layer (t=0 reads)
    for (int l = 0; l < 3; ++l)
        hipMemsetAsync(hreg + (size_t)(l * 2) * 32768, 0, 32768 * sizeof(short), stream);

    {   // weight regions: [l0x,l0td,l0hh, l1x,l1bu,l1td,l1hh, l2x,l2bu,l2hh]
        WConv wa;
        const float* srcs[10] = {W_ih[0], W_ih[0], W_hh[0],
                                 W_ih[1], W_ih[1], W_ih[1], W_hh[1],
                                 W_ih[2], W_ih[2], W_hh[2]};
        const int rss[10] = {1024, 1024, 512, 1536, 1536, 1536, 512, 1024, 1024, 512};
        const int cos[10] = {0, 512, 0, 0, 512, 1024, 0, 0, 512, 0};
        for (int r = 0; r < 10; ++r) { wa.src[r] = srcs[r]; wa.rs[r] = rss[r]; wa.co[r] = cos[r]; }
        wa.dst = wreg;
        conv_w<<<dim3(512, 10), 256, 0, stream>>>(wa);
    }
    {
        XConv xa;
        xa.src[0] = x[0]; xa.src[1] = x[1]; xa.src[2] = x[2];
        xa.dst = xreg;
        conv_x<<<dim3(4096, 3), 256, 0, stream>>>(xa);
    }

    const int WX[3] = {0, 3, 7}, WTD[3] = {1, 5, -1}, WBU[3] = {-1, 4, 8}, WHH[3] = {2, 6, 9};

    for (int t = 0; t < TT; ++t) {
        const int slot_r = t & 1, slot_w = (t + 1) & 1;
        for (int l = 0; l < 3; ++l) {
            Stage s;
            s.dx = dx; s.bih = b_ih[l]; s.bhh = b_hh[l];
            s.out = out; s.cst = cst; s.l = l; s.t = t;
            s.hdst = hreg + (size_t)(l * 2 + slot_w) * 32768;
            int ns = 0;
            // x segment (scale: 1 for l==0, d_bottom otherwise)
            s.ap[ns] = xreg + (size_t)l * 8388608 + (size_t)t * 32768;
            s.wp[ns] = wreg + (size_t)WX[l] * 1048576;
            s.sel[ns] = (l == 0) ? 2 : 0; ns++;
            if (l > 0) {  // bottom-up h_new[l-1] at t (slot just written), scale d_bottom
                s.ap[ns] = hreg + (size_t)((l - 1) * 2 + slot_w) * 32768;
                s.wp[ns] = wreg + (size_t)WBU[l] * 1048576;
                s.sel[ns] = 0; ns++;
            }
            if (l < 2) {  // top-down h_prev[l+1] at t-1, scale d
                s.ap[ns] = hreg + (size_t)((l + 1) * 2 + slot_r) * 32768;
                s.wp[ns] = wreg + (size_t)WTD[l] * 1048576;
                s.sel[ns] = 1; ns++;
            }
            // recurrent h_prev[l] at t-1, scale 1
            s.ap[ns] = hreg + (size_t)(l * 2 + slot_r) * 32768;
            s.wp[ns] = wreg + (size_t)WHH[l] * 1048576;
            s.sel[ns] = 2; ns++;
            s.nseg = ns;
            // fill unused descriptor slots with valid pointers (never read)
            for (int r = ns; r < 4; ++r) { s.ap[r] = s.ap[0]; s.wp[r] = s.wp[0]; s.sel[r] = 2; }
            stage_kernel<<<dim3(32, 4), 512, 0, stream>>>(s);
        }
    }
}